// Round 1
// baseline (1849.781 us; speedup 1.0000x reference)
//
#include <hip/hip_runtime.h>

namespace {

constexpr int   B    = 1024;
constexpr int   C    = 256;
constexpr int   CI   = 128;
constexpr int   V    = 90;
constexpr int   SP   = 92;        // padded V stride (23 float4s)
constexpr int   NT4  = SP / 4;    // 23
constexpr float EPSV = 1e-5f;

__device__ __forceinline__ float4 f4fma(float s, float4 x, float4 a) {
  a.x += s * x.x; a.y += s * x.y; a.z += s * x.z; a.w += s * x.w; return a;
}

// ---------------- K0: fold BN into conv weights ----------------
__global__ __launch_bounds__(256) void k0_fold(
    const float* __restrict__ gg,  const float* __restrict__ gbe, const float* __restrict__ gme, const float* __restrict__ gva,
    const float* __restrict__ gw,  const float* __restrict__ gbi,
    const float* __restrict__ tg,  const float* __restrict__ tbe, const float* __restrict__ tme, const float* __restrict__ tva,
    const float* __restrict__ tw,  const float* __restrict__ tbi,
    const float* __restrict__ pg,  const float* __restrict__ pbe, const float* __restrict__ pme, const float* __restrict__ pva,
    const float* __restrict__ pw,  const float* __restrict__ pbi,
    const float* __restrict__ Ww,  const float* __restrict__ Wb,
    const float* __restrict__ Wg,  const float* __restrict__ Wbe, const float* __restrict__ Wme, const float* __restrict__ Wva,
    float* __restrict__ wgo, float* __restrict__ bgo,
    float* __restrict__ wto, float* __restrict__ bto,
    float* __restrict__ wpo, float* __restrict__ bpo,
    float* __restrict__ wWo, float* __restrict__ bWo)
{
  __shared__ float red[4];
  const int blk = blockIdx.x, tid = threadIdx.x;
  if (blk < 3 * CI) {
    const int p = blk >> 7, o = blk & (CI - 1);
    const float *ga, *be, *me, *va, *wm, *bi;
    float *wo, *bo;
    if (p == 0)      { ga = gg; be = gbe; me = gme; va = gva; wm = gw; bi = gbi; wo = wgo; bo = bgo; }
    else if (p == 1) { ga = tg; be = tbe; me = tme; va = tva; wm = tw; bi = tbi; wo = wto; bo = bto; }
    else             { ga = pg; be = pbe; me = pme; va = pva; wm = pw; bi = pbi; wo = wpo; bo = bpo; }
    float s = ga[tid] * rsqrtf(va[tid] + EPSV);
    float t = be[tid] - me[tid] * s;
    float w = wm[o * C + tid];
    wo[o * C + tid] = w * s;
    float part = t * w;
    for (int off = 32; off; off >>= 1) part += __shfl_down(part, off);
    if ((tid & 63) == 0) red[tid >> 6] = part;
    __syncthreads();
    if (tid == 0) bo[o] = bi[o] + red[0] + red[1] + red[2] + red[3];
  } else {
    const int c = blk - 3 * CI;
    float sW = Wg[c] * rsqrtf(Wva[c] + EPSV);
    if (tid < CI) wWo[c * CI + tid] = Ww[c * CI + tid] * sW;
    if (tid == 0) bWo[c] = Wb[c] * sW + Wbe[c] - Wme[c] * sW;
  }
}

// ---------------- K1: folded convs (theta, phi, g_x1, g_x2) + means ----------------
__global__ __launch_bounds__(256) void k1_conv(
    const float* __restrict__ x1, const float* __restrict__ x2,
    const float* __restrict__ wg, const float* __restrict__ bg,
    const float* __restrict__ wt, const float* __restrict__ bt,
    const float* __restrict__ wp, const float* __restrict__ bp,
    float* __restrict__ theta, float* __restrict__ phi,
    float* __restrict__ g1all, float* __restrict__ g2all,   // live in d_out regions
    float* __restrict__ m1t, float* __restrict__ x2cm, float* __restrict__ x1am)
{
  __shared__ float xs[C * SP];   // 94208 B
  __shared__ float red[4];
  const int b = blockIdx.x, tid = threadIdx.x;

  auto stage = [&](const float* __restrict__ xb) {
    const float4* xb4 = (const float4*)xb;
    for (int l = tid; l < C * V / 4; l += 256) {
      float4 xv = xb4[l];
      int i0 = 4 * l;
      int c0 = i0 / V,       v0 = i0 - c0 * V;       xs[c0 * SP + v0] = xv.x;
      int i1 = i0 + 1, c1 = i1 / V, v1 = i1 - c1 * V; xs[c1 * SP + v1] = xv.y;
      int i2 = i0 + 2, c2 = i2 / V, v2 = i2 - c2 * V; xs[c2 * SP + v2] = xv.z;
      int i3 = i0 + 3, c3 = i3 / V, v3 = i3 - c3 * V; xs[c3 * SP + v3] = xv.w;
    }
    // zero the v-pads so float4 tails are exact zeros
    xs[tid * SP + V]     = 0.f;
    xs[tid * SP + V + 1] = 0.f;
  };

  // out[o,v] = sum_c w[o,c]*xs[c,v] + bias[o]; 4-row register blocking
  auto conv4 = [&](const float* __restrict__ w, const float* __restrict__ bias, float* __restrict__ dst) {
    for (int t = tid; t < (CI / 4) * NT4; t += 256) {
      int og = t / NT4, v4 = t - og * NT4;
      int o = og * 4, vb = v4 * 4;
      const float* w0 = w + (size_t)(o + 0) * C;
      const float* w1 = w + (size_t)(o + 1) * C;
      const float* w2 = w + (size_t)(o + 2) * C;
      const float* w3 = w + (size_t)(o + 3) * C;
      float4 a0 = {0,0,0,0}, a1 = a0, a2 = a0, a3 = a0;
      for (int c = 0; c < C; ++c) {
        float4 xv = *(const float4*)&xs[c * SP + vb];
        a0 = f4fma(w0[c], xv, a0);
        a1 = f4fma(w1[c], xv, a1);
        a2 = f4fma(w2[c], xv, a2);
        a3 = f4fma(w3[c], xv, a3);
      }
      float b0 = bias[o + 0], b1 = bias[o + 1], b2 = bias[o + 2], b3 = bias[o + 3];
      a0.x += b0; a1.x += b1; a2.x += b2; a3.x += b3;
      if (vb + 1 < V) { a0.y += b0; a1.y += b1; a2.y += b2; a3.y += b3; }
      if (vb + 2 < V) { a0.z += b0; a1.z += b1; a2.z += b2; a3.z += b3; }
      if (vb + 3 < V) { a0.w += b0; a1.w += b1; a2.w += b2; a3.w += b3; }
      *(float4*)&dst[(o + 0) * SP + vb] = a0;
      *(float4*)&dst[(o + 1) * SP + vb] = a1;
      *(float4*)&dst[(o + 2) * SP + vb] = a2;
      *(float4*)&dst[(o + 3) * SP + vb] = a3;
    }
  };

  // ---- x1 phase
  stage(x1 + (size_t)b * C * V);
  __syncthreads();
  {
    float s = 0.f;
    for (int v = 0; v < V; ++v) s += xs[tid * SP + v];
    m1t[(size_t)b * C + tid] = s * (1.f / V);
    for (int off = 32; off; off >>= 1) s += __shfl_down(s, off);
    if ((tid & 63) == 0) red[tid >> 6] = s;
  }
  __syncthreads();
  if (tid == 0) x1am[b] = (red[0] + red[1] + red[2] + red[3]) * (1.f / (C * V));
  conv4(wg, bg, g1all + (size_t)b * C * V);
  conv4(wt, bt, theta + (size_t)b * CI * SP);
  __syncthreads();
  // ---- x2 phase
  stage(x2 + (size_t)b * C * V);
  __syncthreads();
  if (tid < V) {
    float s = 0.f;
    for (int c = 0; c < C; ++c) s += xs[c * SP + tid];
    x2cm[(size_t)b * SP + tid] = s * (1.f / C);
  }
  conv4(wg, bg, g2all + (size_t)b * C * V);
  conv4(wp, bp, phi + (size_t)b * CI * SP);
}

// ---------------- K2: attention scores + softmax stats ----------------
__global__ __launch_bounds__(256) void k2_scores(
    const float* __restrict__ theta, const float* __restrict__ phi,
    float* __restrict__ et, float* __restrict__ es,
    float* __restrict__ etrm, float* __restrict__ etrsi,
    float* __restrict__ etcm, float* __restrict__ etcsi,
    float* __restrict__ esrm, float* __restrict__ esrsi,
    float* __restrict__ escm, float* __restrict__ escsi)
{
  __shared__ float th[CI * SP];
  __shared__ float ph[CI * SP];
  __shared__ float eb[CI * CI];   // total LDS 159744 B
  const int b = blockIdx.x, tid = threadIdx.x;
  {
    const float4* ts = (const float4*)(theta + (size_t)b * CI * SP);
    const float4* ps = (const float4*)(phi   + (size_t)b * CI * SP);
    float4* th4 = (float4*)th; float4* ph4 = (float4*)ph;
    for (int l = tid; l < CI * SP / 4; l += 256) { th4[l] = ts[l]; ph4[l] = ps[l]; }
  }
  __syncthreads();
  // e_time[i,j] = sum_v th[i,v]*ph[j,v] ; 4x4 register tile
  float* etb = et + (size_t)b * CI * CI;
  for (int t = tid; t < 32 * 32; t += 256) {
    int ig = t >> 5, jg = t & 31;
    int i = ig * 4, j = jg * 4;
    float acc[4][4] = {};
    for (int v = 0; v < V; ++v) {
      float tt[4], pp[4];
#pragma unroll
      for (int r = 0; r < 4; ++r) tt[r] = th[(i + r) * SP + v];
#pragma unroll
      for (int s = 0; s < 4; ++s) pp[s] = ph[(j + s) * SP + v];
#pragma unroll
      for (int r = 0; r < 4; ++r)
#pragma unroll
        for (int s = 0; s < 4; ++s) acc[r][s] += tt[r] * pp[s];
    }
#pragma unroll
    for (int r = 0; r < 4; ++r) {
      float4 o4 = {acc[r][0], acc[r][1], acc[r][2], acc[r][3]};
      *(float4*)&eb[(i + r) * CI + j]  = o4;
      *(float4*)&etb[(i + r) * CI + j] = o4;
    }
  }
  __syncthreads();
  if (tid < CI) {            // row stats (attn_time_1)
    int i = tid;
    float m = -1e30f;
    for (int j = 0; j < CI; ++j) m = fmaxf(m, eb[i * CI + j]);
    float s = 0.f;
    for (int j = 0; j < CI; ++j) s += __expf(eb[i * CI + j] - m);
    etrm[(size_t)b * CI + i] = m; etrsi[(size_t)b * CI + i] = 1.f / s;
  } else {                   // col stats (attn_time_2)
    int j = tid - CI;
    float m = -1e30f;
    for (int i = 0; i < CI; ++i) m = fmaxf(m, eb[i * CI + j]);
    float s = 0.f;
    for (int i = 0; i < CI; ++i) s += __expf(eb[i * CI + j] - m);
    etcm[(size_t)b * CI + j] = m; etcsi[(size_t)b * CI + j] = 1.f / s;
  }
  __syncthreads();
  // e_space[i,j] = sum_c th[c,i]*ph[c,j]  (i,j < V)
  float* esb = es + (size_t)b * V * SP;
  for (int t = tid; t < V * NT4; t += 256) {
    int i = t / NT4, j4 = t - i * NT4;
    int jb = j4 * 4;
    float4 acc = {0,0,0,0};
    for (int c = 0; c < CI; ++c) {
      float tv = th[c * SP + i];
      float4 p4 = *(const float4*)&ph[c * SP + jb];
      acc = f4fma(tv, p4, acc);
    }
    *(float4*)&eb[i * SP + jb]  = acc;   // pads are exact 0 (phi pads are 0)
    *(float4*)&esb[i * SP + jb] = acc;
  }
  __syncthreads();
  if (tid < V) {             // row stats (attn_space_2)
    int i = tid;
    float m = -1e30f;
    for (int w = 0; w < V; ++w) m = fmaxf(m, eb[i * SP + w]);
    float s = 0.f;
    for (int w = 0; w < V; ++w) s += __expf(eb[i * SP + w] - m);
    esrm[(size_t)b * SP + i] = m; esrsi[(size_t)b * SP + i] = 1.f / s;
  } else if (tid >= 128 && tid < 128 + V) {   // col stats (attn_space_1)
    int j = tid - 128;
    float m = -1e30f;
    for (int i = 0; i < V; ++i) m = fmaxf(m, eb[i * SP + j]);
    float s = 0.f;
    for (int i = 0; i < V; ++i) s += __expf(eb[i * SP + j] - m);
    escm[(size_t)b * SP + j] = m; escsi[(size_t)b * SP + j] = 1.f / s;
  }
}

// ---------------- K3: softmax-on-the-fly sandwich products + Wop + residuals ----------------
__global__ __launch_bounds__(256) void k3_out(
    const float* __restrict__ x1, const float* __restrict__ x2,
    const float* __restrict__ et, const float* __restrict__ es,
    const float* __restrict__ etrm, const float* __restrict__ etrsi,
    const float* __restrict__ etcm, const float* __restrict__ etcsi,
    const float* __restrict__ esrm, const float* __restrict__ esrsi,
    const float* __restrict__ escm, const float* __restrict__ escsi,
    const float* __restrict__ wW, const float* __restrict__ bW,
    const float* __restrict__ m1t, const float* __restrict__ x2cm, const float* __restrict__ x1am,
    float* out)
{
  __shared__ float A[CI * CI];   // attn matrix (time: stride CI; space: stride SP)
  __shared__ float G[CI * SP];   // g_x / z buffer
  __shared__ float T[CI * SP];   // intermediate A_t @ g
  const int b = blockIdx.x, tid = threadIdx.x;
  const float* etb = et + (size_t)b * CI * CI;
  const float* esb = es + (size_t)b * V * SP;
  float* out1 = out + (size_t)b * C * V;
  float* out2 = out + (size_t)B * C * V + (size_t)b * C * V;

  auto matmulT = [&]() {   // T = A(CIxCI) @ G(CIxSP)
    for (int t = tid; t < 32 * NT4; t += 256) {
      int ig = t / NT4, v4 = t - ig * NT4;
      int i = ig * 4, vb = v4 * 4;
      float4 a0 = {0,0,0,0}, a1 = a0, a2 = a0, a3 = a0;
      for (int j = 0; j < CI; ++j) {
        float4 g4 = *(const float4*)&G[j * SP + vb];
        a0 = f4fma(A[(i + 0) * CI + j], g4, a0);
        a1 = f4fma(A[(i + 1) * CI + j], g4, a1);
        a2 = f4fma(A[(i + 2) * CI + j], g4, a2);
        a3 = f4fma(A[(i + 3) * CI + j], g4, a3);
      }
      *(float4*)&T[(i + 0) * SP + vb] = a0;
      *(float4*)&T[(i + 1) * SP + vb] = a1;
      *(float4*)&T[(i + 2) * SP + vb] = a2;
      *(float4*)&T[(i + 3) * SP + vb] = a3;
    }
  };
  auto zmul = [&]() {      // G = T(CIxV) @ A_space(VxSP)
    for (int t = tid; t < 32 * NT4; t += 256) {
      int ig = t / NT4, w4 = t - ig * NT4;
      int i = ig * 4, wb = w4 * 4;
      float4 a0 = {0,0,0,0}, a1 = a0, a2 = a0, a3 = a0;
      for (int v = 0; v < V; ++v) {
        float4 s4 = *(const float4*)&A[v * SP + wb];
        a0 = f4fma(T[(i + 0) * SP + v], s4, a0);
        a1 = f4fma(T[(i + 1) * SP + v], s4, a1);
        a2 = f4fma(T[(i + 2) * SP + v], s4, a2);
        a3 = f4fma(T[(i + 3) * SP + v], s4, a3);
      }
      *(float4*)&G[(i + 0) * SP + wb] = a0;
      *(float4*)&G[(i + 1) * SP + wb] = a1;
      *(float4*)&G[(i + 2) * SP + wb] = a2;
      *(float4*)&G[(i + 3) * SP + wb] = a3;
    }
  };
  // dst[c,v] = xb[c,v] + (useM1t ? m1t[b,c] : am + x2cm[b,v]) + sum_i wW[c,i]*G[i,v] + bW[c]
  auto outmul = [&](const float* __restrict__ xb, float* __restrict__ dst, bool useM1t, float am) {
    for (int t = tid; t < (C / 4) * NT4; t += 256) {
      int cg = t / NT4, v4 = t - cg * NT4;
      int c = cg * 4, vb = v4 * 4;
      const float* w0 = wW + (size_t)(c + 0) * CI;
      const float* w1 = wW + (size_t)(c + 1) * CI;
      const float* w2 = wW + (size_t)(c + 2) * CI;
      const float* w3 = wW + (size_t)(c + 3) * CI;
      float4 a0 = {0,0,0,0}, a1 = a0, a2 = a0, a3 = a0;
      for (int i = 0; i < CI; ++i) {
        float4 z4 = *(const float4*)&G[i * SP + vb];
        a0 = f4fma(w0[i], z4, a0);
        a1 = f4fma(w1[i], z4, a1);
        a2 = f4fma(w2[i], z4, a2);
        a3 = f4fma(w3[i], z4, a3);
      }
      float base0 = bW[c + 0] + (useM1t ? m1t[(size_t)b * C + c + 0] : am);
      float base1 = bW[c + 1] + (useM1t ? m1t[(size_t)b * C + c + 1] : am);
      float base2 = bW[c + 2] + (useM1t ? m1t[(size_t)b * C + c + 2] : am);
      float base3 = bW[c + 3] + (useM1t ? m1t[(size_t)b * C + c + 3] : am);
      float r0[4] = {a0.x, a0.y, a0.z, a0.w};
      float r1[4] = {a1.x, a1.y, a1.z, a1.w};
      float r2[4] = {a2.x, a2.y, a2.z, a2.w};
      float r3[4] = {a3.x, a3.y, a3.z, a3.w};
#pragma unroll
      for (int k = 0; k < 4; ++k) {
        int v = vb + k;
        if (v < V) {
          float addv = useM1t ? 0.f : x2cm[(size_t)b * SP + v];
          dst[(c + 0) * V + v] = r0[k] + base0 + addv + xb[(c + 0) * V + v];
          dst[(c + 1) * V + v] = r1[k] + base1 + addv + xb[(c + 1) * V + v];
          dst[(c + 2) * V + v] = r2[k] + base2 + addv + xb[(c + 2) * V + v];
          dst[(c + 3) * V + v] = r3[k] + base3 + addv + xb[(c + 3) * V + v];
        }
      }
    }
  };

  // ---------- phase A: out2 = x2 + m1t + Wop(A_t1 @ g_x2 @ A_s1) ----------
  for (int n = tid; n < CI * CI; n += 256) {
    int i = n >> 7;
    A[n] = __expf(etb[n] - etrm[(size_t)b * CI + i]) * etrsi[(size_t)b * CI + i];
  }
  {
    const float4* gsrc = (const float4*)out2;  // g_x2 staged here by K1
    float4* G4 = (float4*)G;
    for (int l = tid; l < CI * SP / 4; l += 256) G4[l] = gsrc[l];
  }
  __syncthreads();
  matmulT();
  __syncthreads();
  for (int n = tid; n < V * SP; n += 256) {     // A_s1[v,w] = exp(es[w,v]-cm[v])*csi[v]
    int v = n / SP, w = n - v * SP;
    float val = 0.f;
    if (w < V) val = __expf(esb[w * SP + v] - escm[(size_t)b * SP + v]) * escsi[(size_t)b * SP + v];
    A[n] = val;
  }
  __syncthreads();
  zmul();
  __syncthreads();
  outmul(x2 + (size_t)b * C * V, out2, /*useM1t=*/true, 0.f);
  __syncthreads();

  // ---------- phase B: out1 = x1 + x2cm + x1am + Wop(A_t2 @ g_x1 @ A_s2) ----------
  for (int n = tid; n < CI * CI; n += 256) {    // A_t2[i,j] = exp(et[j,i]-cm[i])*csi[i]
    int r = n >> 7, cc = n & 127;
    A[cc * CI + r] = __expf(etb[n] - etcm[(size_t)b * CI + cc]) * etcsi[(size_t)b * CI + cc];
  }
  {
    const float4* gsrc = (const float4*)out1;  // g_x1 staged here by K1
    float4* G4 = (float4*)G;
    for (int l = tid; l < CI * SP / 4; l += 256) G4[l] = gsrc[l];
  }
  __syncthreads();
  matmulT();
  __syncthreads();
  for (int n = tid; n < V * SP; n += 256) {     // A_s2[v,w] = exp(es[v,w]-rm[v])*rsi[v]
    int v = n / SP, w = n - v * SP;
    float val = 0.f;
    if (w < V) val = __expf(esb[v * SP + w] - esrm[(size_t)b * SP + v]) * esrsi[(size_t)b * SP + v];
    A[n] = val;
  }
  __syncthreads();
  zmul();
  __syncthreads();
  outmul(x1 + (size_t)b * C * V, out1, /*useM1t=*/false, x1am[b]);
}

} // namespace

extern "C" void kernel_launch(void* const* d_in, const int* in_sizes, int n_in,
                              void* d_out, int out_size, void* d_ws, size_t ws_size,
                              hipStream_t stream)
{
  (void)in_sizes; (void)n_in; (void)out_size; (void)ws_size;
  const float* x1  = (const float*)d_in[0];
  const float* x2  = (const float*)d_in[1];
  const float* gg  = (const float*)d_in[2];
  const float* gbe = (const float*)d_in[3];
  const float* gme = (const float*)d_in[4];
  const float* gva = (const float*)d_in[5];
  const float* gw  = (const float*)d_in[6];
  const float* gbi = (const float*)d_in[7];
  const float* tg  = (const float*)d_in[8];
  const float* tbe = (const float*)d_in[9];
  const float* tme = (const float*)d_in[10];
  const float* tva = (const float*)d_in[11];
  const float* tw  = (const float*)d_in[12];
  const float* tbi = (const float*)d_in[13];
  const float* pg  = (const float*)d_in[14];
  const float* pbe = (const float*)d_in[15];
  const float* pme = (const float*)d_in[16];
  const float* pva = (const float*)d_in[17];
  const float* pw  = (const float*)d_in[18];
  const float* pbi = (const float*)d_in[19];
  const float* Ww  = (const float*)d_in[20];
  const float* Wb  = (const float*)d_in[21];
  const float* Wg  = (const float*)d_in[22];
  const float* Wbe = (const float*)d_in[23];
  const float* Wme = (const float*)d_in[24];
  const float* Wva = (const float*)d_in[25];
  // d_in[26..33] (qt/ks/qs/kt) are dead: softmax over a singleton axis == 1.

  float* out = (float*)d_out;
  float* ws  = (float*)d_ws;

  size_t off = 0;
  auto A_ = [&](size_t n) { size_t r = off; off += n; return r; };
  const size_t oWG = A_(CI * C), oWT = A_(CI * C), oWP = A_(CI * C), oWW = A_((size_t)C * CI);
  const size_t oBG = A_(CI), oBT = A_(CI), oBP = A_(CI), oBW = A_(C);
  const size_t oTH = A_((size_t)B * CI * SP), oPH = A_((size_t)B * CI * SP);
  const size_t oET = A_((size_t)B * CI * CI), oES = A_((size_t)B * V * SP);
  const size_t oETRM = A_((size_t)B * CI), oETRS = A_((size_t)B * CI);
  const size_t oETCM = A_((size_t)B * CI), oETCS = A_((size_t)B * CI);
  const size_t oESRM = A_((size_t)B * SP), oESRS = A_((size_t)B * SP);
  const size_t oESCM = A_((size_t)B * SP), oESCS = A_((size_t)B * SP);
  const size_t oM1T = A_((size_t)B * C), oX2CM = A_((size_t)B * SP), oX1AM = A_(B);
  // total ws use: ~203 MB

  k0_fold<<<dim3(3 * CI + C), dim3(256), 0, stream>>>(
      gg, gbe, gme, gva, gw, gbi,
      tg, tbe, tme, tva, tw, tbi,
      pg, pbe, pme, pva, pw, pbi,
      Ww, Wb, Wg, Wbe, Wme, Wva,
      ws + oWG, ws + oBG, ws + oWT, ws + oBT, ws + oWP, ws + oBP, ws + oWW, ws + oBW);

  k1_conv<<<dim3(B), dim3(256), 0, stream>>>(
      x1, x2,
      ws + oWG, ws + oBG, ws + oWT, ws + oBT, ws + oWP, ws + oBP,
      ws + oTH, ws + oPH,
      out, out + (size_t)B * C * V,
      ws + oM1T, ws + oX2CM, ws + oX1AM);

  k2_scores<<<dim3(B), dim3(256), 0, stream>>>(
      ws + oTH, ws + oPH, ws + oET, ws + oES,
      ws + oETRM, ws + oETRS, ws + oETCM, ws + oETCS,
      ws + oESRM, ws + oESRS, ws + oESCM, ws + oESCS);

  k3_out<<<dim3(B), dim3(256), 0, stream>>>(
      x1, x2, ws + oET, ws + oES,
      ws + oETRM, ws + oETRS, ws + oETCM, ws + oETCS,
      ws + oESRM, ws + oESRS, ws + oESCM, ws + oESCS,
      ws + oWW, ws + oBW, ws + oM1T, ws + oX2CM, ws + oX1AM, out);
}

// Round 4
// 463.938 us; speedup vs baseline: 3.9871x; 3.9871x over previous
//
#include <hip/hip_runtime.h>

namespace {

constexpr int B = 1024;

using u16 = unsigned short;
using u32 = unsigned int;

typedef __attribute__((ext_vector_type(8))) short bf16x8;
typedef __attribute__((ext_vector_type(4))) float f32x4;

#define MFMA16(a, b, c) __builtin_amdgcn_mfma_f32_16x16x32_bf16(a, b, c, 0, 0, 0)

__device__ __forceinline__ u16 f2bf(float f) {
  u32 u = __builtin_bit_cast(u32, f);
  u += 0x7FFFu + ((u >> 16) & 1u);          // RNE
  return (u16)(u >> 16);
}
__device__ __forceinline__ float bf2f(u16 s) {
  u32 u = ((u32)s) << 16;
  return __builtin_bit_cast(float, u);
}
__device__ __forceinline__ u32 packbf2(float a, float b) {
  return (u32)f2bf(a) | ((u32)f2bf(b) << 16);
}

// ---------------- K0: fold BN into conv weights ----------------
// g/W weights: single bf16. theta/phi weights: hi/lo bf16 split (for fp32-exact scores).
__global__ __launch_bounds__(256) void k0_fold(
    const float* __restrict__ gg, const float* __restrict__ gbe, const float* __restrict__ gme, const float* __restrict__ gva,
    const float* __restrict__ gw, const float* __restrict__ gbi,
    const float* __restrict__ tg, const float* __restrict__ tbe, const float* __restrict__ tme, const float* __restrict__ tva,
    const float* __restrict__ tw, const float* __restrict__ tbi,
    const float* __restrict__ pg, const float* __restrict__ pbe, const float* __restrict__ pme, const float* __restrict__ pva,
    const float* __restrict__ pw, const float* __restrict__ pbi,
    const float* __restrict__ Ww, const float* __restrict__ Wb,
    const float* __restrict__ Wg2, const float* __restrict__ Wbe, const float* __restrict__ Wme, const float* __restrict__ Wva,
    u16* __restrict__ wgo, float* __restrict__ bgo,
    u16* __restrict__ wthi, u16* __restrict__ wtlo, float* __restrict__ bto,
    u16* __restrict__ wphi, u16* __restrict__ wplo, float* __restrict__ bpo,
    u16* __restrict__ wWo, float* __restrict__ bWo)
{
  __shared__ float red[4];
  const int blk = blockIdx.x, tid = threadIdx.x;
  if (blk < 384) {
    const int p = blk >> 7, o = blk & 127;
    const float *ga, *be, *me, *va, *wm, *bi;
    if (p == 0)      { ga = gg; be = gbe; me = gme; va = gva; wm = gw; bi = gbi; }
    else if (p == 1) { ga = tg; be = tbe; me = tme; va = tva; wm = tw; bi = tbi; }
    else             { ga = pg; be = pbe; me = pme; va = pva; wm = pw; bi = pbi; }
    float s = ga[tid] * rsqrtf(va[tid] + 1e-5f);
    float t = be[tid] - me[tid] * s;
    float wv = wm[o * 256 + tid];
    float val = wv * s;
    if (p == 0) {
      wgo[o * 256 + tid] = f2bf(val);
    } else {
      u16 hi = f2bf(val);
      u16 lo = f2bf(val - bf2f(hi));
      if (p == 1) { wthi[o * 256 + tid] = hi; wtlo[o * 256 + tid] = lo; }
      else        { wphi[o * 256 + tid] = hi; wplo[o * 256 + tid] = lo; }
    }
    float part = t * wv;
#pragma unroll
    for (int off = 32; off; off >>= 1) part += __shfl_down(part, off);
    if ((tid & 63) == 0) red[tid >> 6] = part;
    __syncthreads();
    if (tid == 0) {
      float bsum = bi[o] + red[0] + red[1] + red[2] + red[3];
      if (p == 0) bgo[o] = bsum; else if (p == 1) bto[o] = bsum; else bpo[o] = bsum;
    }
  } else {
    const int c = blk - 384;
    float sW = Wg2[c] * rsqrtf(Wva[c] + 1e-5f);
    if (tid < 128) wWo[c * 128 + tid] = f2bf(Ww[c * 128 + tid] * sW);
    if (tid == 0) bWo[c] = Wb[c] * sW + Wbe[c] - Wme[c] * sW;
  }
}

// ---------------- K1: split-precision convs -> thT/phT fp32 [90][128], g bf16, means ----------------
__global__ __launch_bounds__(512) void k1_conv(
    const float* __restrict__ x1, const float* __restrict__ x2,
    const u16* __restrict__ wG, const float* __restrict__ bG,
    const u16* __restrict__ wTh, const u16* __restrict__ wTl, const float* __restrict__ bT,
    const u16* __restrict__ wPh, const u16* __restrict__ wPl, const float* __restrict__ bP,
    float* __restrict__ thT, float* __restrict__ phT,
    u16* __restrict__ gout,
    float* __restrict__ m1t, float* __restrict__ x2cm, float* __restrict__ x1am)
{
  __shared__ u16 xhi[96 * 264];      // 50688 B
  __shared__ u16 xlo[96 * 264];      // 50688 B  (total 101376 + red)
  __shared__ float red[8];
  const int b = blockIdx.x, tid = threadIdx.x;
  const int l = tid & 63, wv = tid >> 6;         // 8 waves
  const int lr = l & 15, lq = l >> 4;
  const int c = tid >> 1, h = tid & 1;

  const float* xb1 = x1 + (size_t)b * 23040;
  const float* xb2 = x2 + (size_t)b * 23040;
  u16* g1d = gout + (size_t)b * 46080;
  u16* g2d = gout + (size_t)(1024 + b) * 46080;
  float* thTb = thT + (size_t)b * 11520;
  float* phTb = phT + (size_t)b * 11520;

  const f32x4 zero = {0.f, 0.f, 0.f, 0.f};

  // stage x (hi/lo split) ; returns this thread's partial row-sum
  auto stage = [&](const float* __restrict__ xb) -> float {
    float s = 0.f;
    const int v2lo = h ? 23 : 0, v2hi = h ? 45 : 23;
    for (int v2 = v2lo; v2 < v2hi; ++v2) {
      float2 f = *(const float2*)(xb + c * 90 + 2 * v2);
      s += f.x + f.y;
      u16 h0 = f2bf(f.x);
      xhi[(2 * v2) * 264 + c] = h0;
      xlo[(2 * v2) * 264 + c] = f2bf(f.x - bf2f(h0));
      u16 h1 = f2bf(f.y);
      xhi[(2 * v2 + 1) * 264 + c] = h1;
      xlo[(2 * v2 + 1) * 264 + c] = f2bf(f.y - bf2f(h1));
    }
    for (int i = tid; i < 1536; i += 512) {
      int v = 90 + (i >> 8), cc = i & 255;
      xhi[v * 264 + cc] = 0; xlo[v * 264 + cc] = 0;
    }
    return s;
  };

  // theta/phi conv: 3-term split MFMA, fp32 output [90][128]
  auto convSplit = [&](const u16* __restrict__ Wh, const u16* __restrict__ Wl,
                       const float* __restrict__ bias, float* __restrict__ dstF) {
    const int mt = wv;
    f32x4 acc[6];
#pragma unroll
    for (int i = 0; i < 6; ++i) acc[i] = zero;
#pragma unroll
    for (int kk = 0; kk < 8; ++kk) {
      bf16x8 ah = *(const bf16x8*)(Wh + (16 * mt + lr) * 256 + kk * 32 + 8 * lq);
      bf16x8 al = *(const bf16x8*)(Wl + (16 * mt + lr) * 256 + kk * 32 + 8 * lq);
#pragma unroll
      for (int nt = 0; nt < 6; ++nt) {
        bf16x8 bh = *(const bf16x8*)&xhi[(16 * nt + lr) * 264 + kk * 32 + 8 * lq];
        bf16x8 bl = *(const bf16x8*)&xlo[(16 * nt + lr) * 264 + kk * 32 + 8 * lq];
        acc[nt] = MFMA16(ah, bh, acc[nt]);
        acc[nt] = MFMA16(ah, bl, acc[nt]);
        acc[nt] = MFMA16(al, bh, acc[nt]);
      }
    }
    const int c0 = 16 * mt + 4 * lq;
    const float4 b4 = *(const float4*)(bias + c0);
#pragma unroll
    for (int nt = 0; nt < 6; ++nt) {
      const int v = 16 * nt + lr;
      if (v < 90) {
        float4 o;
        o.x = acc[nt][0] + b4.x; o.y = acc[nt][1] + b4.y;
        o.z = acc[nt][2] + b4.z; o.w = acc[nt][3] + b4.w;
        *(float4*)(dstF + v * 128 + c0) = o;
      }
    }
  };

  // g conv: plain bf16 MFMA, bf16 output [96][128] (zeros for v>=90)
  auto convG = [&](const u16* __restrict__ Wm, const float* __restrict__ bias, u16* __restrict__ dst) {
    const int mt = wv;
    f32x4 acc[6];
#pragma unroll
    for (int i = 0; i < 6; ++i) acc[i] = zero;
#pragma unroll
    for (int kk = 0; kk < 8; ++kk) {
      bf16x8 a = *(const bf16x8*)(Wm + (16 * mt + lr) * 256 + kk * 32 + 8 * lq);
#pragma unroll
      for (int nt = 0; nt < 6; ++nt) {
        bf16x8 bb = *(const bf16x8*)&xhi[(16 * nt + lr) * 264 + kk * 32 + 8 * lq];
        acc[nt] = MFMA16(a, bb, acc[nt]);
      }
    }
    const int c0 = 16 * mt + 4 * lq;
    const float4 b4 = *(const float4*)(bias + c0);
#pragma unroll
    for (int nt = 0; nt < 6; ++nt) {
      const int v = 16 * nt + lr;
      uint2 pk;
      if (v < 90) {
        pk.x = packbf2(acc[nt][0] + b4.x, acc[nt][1] + b4.y);
        pk.y = packbf2(acc[nt][2] + b4.z, acc[nt][3] + b4.w);
      } else { pk.x = 0u; pk.y = 0u; }
      *(uint2*)(dst + v * 128 + c0) = pk;
    }
  };

  // ---- x1 phase
  {
    float s = stage(xb1);
    float s2 = s + __shfl_down(s, 1);
    if (h == 0) m1t[b * 256 + c] = s2 * (1.f / 90.f);
    float t = s;
#pragma unroll
    for (int o = 32; o; o >>= 1) t += __shfl_down(t, o);
    if (l == 0) red[wv] = t;
  }
  __syncthreads();
  if (tid == 0) {
    float a = 0.f;
#pragma unroll
    for (int i = 0; i < 8; ++i) a += red[i];
    x1am[b] = a * (1.f / 23040.f);
  }
  convSplit(wTh, wTl, bT, thTb);
  convG(wG, bG, g1d);
  __syncthreads();
  // ---- x2 phase
  stage(xb2);
  __syncthreads();
  if (tid < 96) {
    float s = 0.f;
    for (int cc = 0; cc < 256; ++cc)
      s += bf2f(xhi[tid * 264 + cc]) + bf2f(xlo[tid * 264 + cc]);
    x2cm[b * 96 + tid] = s * (1.f / 256.f);
  }
  convSplit(wPh, wPl, bP, phTb);
  convG(wG, bG, g2d);
}

// ---------------- K2: fp32-exact scores via 3-term split MFMA + softmax -> bf16 attn ----------------
__global__ __launch_bounds__(256) void k2_attn(
    const float* __restrict__ thTg_, const float* __restrict__ phTg_,
    u16* __restrict__ At1g, u16* __restrict__ At2g,
    u16* __restrict__ As1g, u16* __restrict__ As2g)
{
  __shared__ __align__(16) char smem[108544];
  u16* s0 = (u16*)smem;
  float* st = (float*)(smem + 106496);   // 512 floats
  float* eL = (float*)smem;              // overlay after staging reads complete

  const int b = blockIdx.x, tid = threadIdx.x;
  const int l = tid & 63, wv = tid >> 6, lr = l & 15, lq = l >> 4;
  const float* thg = thTg_ + (size_t)b * 11520;
  const float* phg = phTg_ + (size_t)b * 11520;
  const f32x4 zero = {0.f, 0.f, 0.f, 0.f};

  // ================= phase 1: e_time (row-major hi/lo, K=96) =================
  u16* th_hi = s0;              // [128][104]
  u16* th_lo = s0 + 13312;
  u16* ph_hi = s0 + 26624;
  u16* ph_lo = s0 + 39936;
  for (int d = tid; d < 2880; d += 256) {
    int v = d >> 5, cq = d & 31;
    float4 t4 = *(const float4*)(thg + v * 128 + 4 * cq);
    float4 p4 = *(const float4*)(phg + v * 128 + 4 * cq);
    float ta[4] = {t4.x, t4.y, t4.z, t4.w};
    float pa[4] = {p4.x, p4.y, p4.z, p4.w};
#pragma unroll
    for (int k = 0; k < 4; ++k) {
      int ci = 4 * cq + k;
      u16 thh = f2bf(ta[k]);
      th_hi[ci * 104 + v] = thh;
      th_lo[ci * 104 + v] = f2bf(ta[k] - bf2f(thh));
      u16 phh = f2bf(pa[k]);
      ph_hi[ci * 104 + v] = phh;
      ph_lo[ci * 104 + v] = f2bf(pa[k] - bf2f(phh));
    }
  }
  for (int d = tid; d < 768; d += 256) {
    int ci = d / 6, v = 90 + d % 6;
    th_hi[ci * 104 + v] = 0; th_lo[ci * 104 + v] = 0;
    ph_hi[ci * 104 + v] = 0; ph_lo[ci * 104 + v] = 0;
  }
  __syncthreads();
  f32x4 accT[2][8];
#pragma unroll
  for (int mi = 0; mi < 2; ++mi)
#pragma unroll
    for (int nt = 0; nt < 8; ++nt) accT[mi][nt] = zero;
#pragma unroll
  for (int mi = 0; mi < 2; ++mi) {
    const int mt = 2 * wv + mi;
#pragma unroll
    for (int kk = 0; kk < 3; ++kk) {
      bf16x8 ah = *(const bf16x8*)&th_hi[(16 * mt + lr) * 104 + kk * 32 + 8 * lq];
      bf16x8 al = *(const bf16x8*)&th_lo[(16 * mt + lr) * 104 + kk * 32 + 8 * lq];
#pragma unroll
      for (int nt = 0; nt < 8; ++nt) {
        bf16x8 bh = *(const bf16x8*)&ph_hi[(16 * nt + lr) * 104 + kk * 32 + 8 * lq];
        bf16x8 bl = *(const bf16x8*)&ph_lo[(16 * nt + lr) * 104 + kk * 32 + 8 * lq];
        accT[mi][nt] = MFMA16(ah, bh, accT[mi][nt]);
        accT[mi][nt] = MFMA16(ah, bl, accT[mi][nt]);
        accT[mi][nt] = MFMA16(al, bh, accT[mi][nt]);
      }
    }
  }
  __syncthreads();   // all staging reads done -> safe to overlay eL
#pragma unroll
  for (int mi = 0; mi < 2; ++mi) {
    const int mt = 2 * wv + mi;
#pragma unroll
    for (int nt = 0; nt < 8; ++nt)
#pragma unroll
      for (int r = 0; r < 4; ++r)
        eL[(16 * nt + lr) * 133 + 16 * mt + 4 * lq + r] = accT[mi][nt][r];
  }
  __syncthreads();
  // stats: st[j]=col-max, st[128+j]=1/colsum; st[256+i]=row-max, st[384+i]=1/rowsum
  if (tid < 128) {
    int j = tid; float m = -1e30f;
    for (int i = 0; i < 128; ++i) m = fmaxf(m, eL[j * 133 + i]);
    float s = 0.f;
    for (int i = 0; i < 128; ++i) s += __expf(eL[j * 133 + i] - m);
    st[j] = m; st[128 + j] = 1.f / s;
  } else {
    int i = tid - 128; float m = -1e30f;
    for (int j = 0; j < 128; ++j) m = fmaxf(m, eL[j * 133 + i]);
    float s = 0.f;
    for (int j = 0; j < 128; ++j) s += __expf(eL[j * 133 + i] - m);
    st[256 + i] = m; st[384 + i] = 1.f / s;
  }
  __syncthreads();
  {
    u32* A1 = (u32*)(At1g + (size_t)b * 16384);
    u32* A2 = (u32*)(At2g + (size_t)b * 16384);
    for (int d = tid; d < 8192; d += 256) {
      int i = d >> 6, jp = d & 63;
      float m1 = st[256 + i], s1 = st[384 + i];
      float a0 = __expf(eL[(2 * jp) * 133 + i] - m1) * s1;
      float a1 = __expf(eL[(2 * jp + 1) * 133 + i] - m1) * s1;
      A1[d] = packbf2(a0, a1);
      float m2 = st[i], s2 = st[128 + i];
      float b0 = __expf(eL[i * 133 + 2 * jp] - m2) * s2;
      float b1 = __expf(eL[i * 133 + 2 * jp + 1] - m2) * s2;
      A2[d] = packbf2(b0, b1);
    }
  }
  __syncthreads();

  // ================= phase 2: e_space (transposed hi/lo, K=128) =================
  u16* tTh = s0;                // [96][136]
  u16* tTl = s0 + 13056;
  u16* pTh = s0 + 26112;
  u16* pTl = s0 + 39168;
  for (int d = tid; d < 2880; d += 256) {
    int v = d >> 5, cq = d & 31;
    float4 t4 = *(const float4*)(thg + v * 128 + 4 * cq);
    float4 p4 = *(const float4*)(phg + v * 128 + 4 * cq);
    float ta[4] = {t4.x, t4.y, t4.z, t4.w};
    float pa[4] = {p4.x, p4.y, p4.z, p4.w};
    u16 th_h[4], th_l[4], ph_h[4], ph_l[4];
#pragma unroll
    for (int k = 0; k < 4; ++k) {
      th_h[k] = f2bf(ta[k]); th_l[k] = f2bf(ta[k] - bf2f(th_h[k]));
      ph_h[k] = f2bf(pa[k]); ph_l[k] = f2bf(pa[k] - bf2f(ph_h[k]));
    }
    uint2 w0, w1;
    w0.x = (u32)th_h[0] | ((u32)th_h[1] << 16); w0.y = (u32)th_h[2] | ((u32)th_h[3] << 16);
    *(uint2*)&tTh[v * 136 + 4 * cq] = w0;
    w1.x = (u32)th_l[0] | ((u32)th_l[1] << 16); w1.y = (u32)th_l[2] | ((u32)th_l[3] << 16);
    *(uint2*)&tTl[v * 136 + 4 * cq] = w1;
    w0.x = (u32)ph_h[0] | ((u32)ph_h[1] << 16); w0.y = (u32)ph_h[2] | ((u32)ph_h[3] << 16);
    *(uint2*)&pTh[v * 136 + 4 * cq] = w0;
    w1.x = (u32)ph_l[0] | ((u32)ph_l[1] << 16); w1.y = (u32)ph_l[2] | ((u32)ph_l[3] << 16);
    *(uint2*)&pTl[v * 136 + 4 * cq] = w1;
  }
  for (int d = tid; d < 192; d += 256) {
    int v = 90 + (d >> 5), cq = d & 31;
    uint2 z; z.x = 0u; z.y = 0u;
    *(uint2*)&tTh[v * 136 + 4 * cq] = z;
    *(uint2*)&tTl[v * 136 + 4 * cq] = z;
    *(uint2*)&pTh[v * 136 + 4 * cq] = z;
    *(uint2*)&pTl[v * 136 + 4 * cq] = z;
  }
  __syncthreads();
  f32x4 accS[9];
#pragma unroll
  for (int it = 0; it < 9; ++it) accS[it] = zero;
#pragma unroll
  for (int it = 0; it < 9; ++it) {
    const int t5 = wv + 4 * it;
    const int mt = t5 / 6, nt = t5 - 6 * (t5 / 6);
#pragma unroll
    for (int kk = 0; kk < 4; ++kk) {
      bf16x8 ah = *(const bf16x8*)&tTh[(16 * mt + lr) * 136 + kk * 32 + 8 * lq];
      bf16x8 al = *(const bf16x8*)&tTl[(16 * mt + lr) * 136 + kk * 32 + 8 * lq];
      bf16x8 bh = *(const bf16x8*)&pTh[(16 * nt + lr) * 136 + kk * 32 + 8 * lq];
      bf16x8 bl = *(const bf16x8*)&pTl[(16 * nt + lr) * 136 + kk * 32 + 8 * lq];
      accS[it] = MFMA16(ah, bh, accS[it]);
      accS[it] = MFMA16(ah, bl, accS[it]);
      accS[it] = MFMA16(al, bh, accS[it]);
    }
  }
  __syncthreads();
  {
    float* esL = (float*)smem;
#pragma unroll
    for (int it = 0; it < 9; ++it) {
      const int t5 = wv + 4 * it;
      const int mt = t5 / 6, nt = t5 - 6 * (t5 / 6);
#pragma unroll
      for (int r = 0; r < 4; ++r)
        esL[(16 * nt + lr) * 101 + 16 * mt + 4 * lq + r] = accS[it][r];
    }
  }
  __syncthreads();
  {
    float* esL = (float*)smem;
    if (tid < 96) {
      int v = tid; float m = -1e30f;
      for (int w2 = 0; w2 < 90; ++w2) m = fmaxf(m, esL[v * 101 + w2]);
      float s = 0.f;
      for (int w2 = 0; w2 < 90; ++w2) s += __expf(esL[v * 101 + w2] - m);
      st[v] = m; st[128 + v] = 1.f / s;
    } else if (tid >= 128 && tid < 224) {
      int v = tid - 128; float m = -1e30f;
      for (int w2 = 0; w2 < 90; ++w2) m = fmaxf(m, esL[w2 * 101 + v]);
      float s = 0.f;
      for (int w2 = 0; w2 < 90; ++w2) s += __expf(esL[w2 * 101 + v] - m);
      st[256 + v] = m; st[384 + v] = 1.f / s;
    }
  }
  __syncthreads();
  {
    float* esL = (float*)smem;
    u32* S1 = (u32*)(As1g + (size_t)b * 9216);
    u32* S2 = (u32*)(As2g + (size_t)b * 9216);
    for (int d = tid; d < 4608; d += 256) {
      int w2 = d / 48, vp = d - (d / 48) * 48;
      int v0 = 2 * vp, v1 = 2 * vp + 1;
      float a0 = __expf(esL[v0 * 101 + w2] - st[v0]) * st[128 + v0];
      float a1 = __expf(esL[v1 * 101 + w2] - st[v1]) * st[128 + v1];
      S1[d] = packbf2(a0, a1);
      float b0 = __expf(esL[w2 * 101 + v0] - st[256 + v0]) * st[384 + v0];
      float b1 = __expf(esL[w2 * 101 + v1] - st[256 + v1]) * st[384 + v1];
      S2[d] = packbf2(b0, b1);
    }
  }
}

// ---------------- K3: T = At@g, Z = T@As, O = W@Z, residual epilogue (unchanged) ----------------
__global__ __launch_bounds__(256) void k3_out(
    const float* __restrict__ x1, const float* __restrict__ x2,
    const u16* __restrict__ At1g, const u16* __restrict__ At2g,
    const u16* __restrict__ As1g, const u16* __restrict__ As2g,
    const u16* __restrict__ wW, const float* __restrict__ bW,
    const float* __restrict__ m1t, const float* __restrict__ x2cm, const float* __restrict__ x1am,
    float* __restrict__ out)
{
  __shared__ u16 gT[96 * 136];
  __shared__ u16 Tb[128 * 104];
  __shared__ u16 ZT[96 * 136];
  const int b = blockIdx.x, tid = threadIdx.x;
  const int l = tid & 63, wv = tid >> 6, lr = l & 15, lq = l >> 4;
  const f32x4 zero = {0.f, 0.f, 0.f, 0.f};

  float* out1 = out + (size_t)b * 23040;
  float* out2 = out + (size_t)23040 * 1024 + (size_t)b * 23040;
  const u16* g1s = (const u16*)out1;
  const u16* g2s = (const u16*)out2;

  auto phase = [&](const u16* __restrict__ gsrc, const u16* __restrict__ At,
                   const u16* __restrict__ AsT, const float* __restrict__ xres,
                   float* __restrict__ dst, bool modeA) {
    for (int i = tid; i < 1536; i += 256) {
      int v = i >> 4, hh = i & 15;
      *(uint4*)&gT[v * 136 + 8 * hh] = ((const uint4*)gsrc)[i];
    }
    __syncthreads();
#pragma unroll
    for (int ni = 0; ni < 2; ++ni) {
      const int nt = 2 * wv + ni;
      f32x4 acc[6];
#pragma unroll
      for (int i = 0; i < 6; ++i) acc[i] = zero;
#pragma unroll
      for (int kk = 0; kk < 4; ++kk) {
        bf16x8 bb = *(const bf16x8*)(At + (16 * nt + lr) * 128 + kk * 32 + 8 * lq);
#pragma unroll
        for (int mt = 0; mt < 6; ++mt) {
          bf16x8 a = *(const bf16x8*)&gT[(16 * mt + lr) * 136 + kk * 32 + 8 * lq];
          acc[mt] = MFMA16(a, bb, acc[mt]);
        }
      }
#pragma unroll
      for (int mt = 0; mt < 6; ++mt) {
        uint2 pk;
        pk.x = packbf2(acc[mt][0], acc[mt][1]);
        pk.y = packbf2(acc[mt][2], acc[mt][3]);
        *(uint2*)&Tb[(16 * nt + lr) * 104 + 16 * mt + 4 * lq] = pk;
      }
    }
    __syncthreads();
    {
      f32x4 acc[2][6];
#pragma unroll
      for (int i = 0; i < 2; ++i)
#pragma unroll
        for (int j = 0; j < 6; ++j) acc[i][j] = zero;
#pragma unroll
      for (int kk = 0; kk < 3; ++kk) {
        bf16x8 a0 = *(const bf16x8*)&Tb[(16 * (2 * wv) + lr) * 104 + kk * 32 + 8 * lq];
        bf16x8 a1 = *(const bf16x8*)&Tb[(16 * (2 * wv + 1) + lr) * 104 + kk * 32 + 8 * lq];
#pragma unroll
        for (int nt = 0; nt < 6; ++nt) {
          bf16x8 bb = *(const bf16x8*)(AsT + (16 * nt + lr) * 96 + kk * 32 + 8 * lq);
          acc[0][nt] = MFMA16(a0, bb, acc[0][nt]);
          acc[1][nt] = MFMA16(a1, bb, acc[1][nt]);
        }
      }
#pragma unroll
      for (int mi = 0; mi < 2; ++mi) {
        const int mt = 2 * wv + mi;
#pragma unroll
        for (int nt = 0; nt < 6; ++nt) {
          uint2 pk;
          pk.x = packbf2(acc[mi][nt][0], acc[mi][nt][1]);
          pk.y = packbf2(acc[mi][nt][2], acc[mi][nt][3]);
          *(uint2*)&ZT[(16 * nt + lr) * 136 + 16 * mt + 4 * lq] = pk;
        }
      }
    }
    __syncthreads();
    const float am = modeA ? 0.f : x1am[b];
#pragma unroll
    for (int mi = 0; mi < 4; ++mi) {
      const int mt = 4 * wv + mi;
      f32x4 acc[6];
#pragma unroll
      for (int i = 0; i < 6; ++i) acc[i] = zero;
#pragma unroll
      for (int kk = 0; kk < 4; ++kk) {
        bf16x8 a = *(const bf16x8*)(wW + (16 * mt + lr) * 128 + kk * 32 + 8 * lq);
#pragma unroll
        for (int nt = 0; nt < 6; ++nt) {
          bf16x8 bb = *(const bf16x8*)&ZT[(16 * nt + lr) * 136 + kk * 32 + 8 * lq];
          acc[nt] = MFMA16(a, bb, acc[nt]);
        }
      }
      const int c0 = 16 * mt + 4 * lq;
      const float4 bw4 = *(const float4*)(bW + c0);
      float bwA[4] = {bw4.x, bw4.y, bw4.z, bw4.w};
      float mA[4] = {0.f, 0.f, 0.f, 0.f};
      if (modeA) {
        const float4 m4 = *(const float4*)(m1t + b * 256 + c0);
        mA[0] = m4.x; mA[1] = m4.y; mA[2] = m4.z; mA[3] = m4.w;
      }
#pragma unroll
      for (int nt = 0; nt < 6; ++nt) {
        const int v = 16 * nt + lr;
        if (v < 90) {
          const float addv = modeA ? 0.f : (am + x2cm[b * 96 + v]);
#pragma unroll
          for (int r = 0; r < 4; ++r) {
            const int c = c0 + r;
            const float extra = modeA ? mA[r] : addv;
            dst[c * 90 + v] = xres[c * 90 + v] + acc[nt][r] + bwA[r] + extra;
          }
        }
      }
    }
    __syncthreads();
  };

  phase(g2s, At1g + (size_t)b * 16384, As1g + (size_t)b * 9216,
        x2 + (size_t)b * 23040, out2, true);
  phase(g1s, At2g + (size_t)b * 16384, As2g + (size_t)b * 9216,
        x1 + (size_t)b * 23040, out1, false);
}

} // namespace

extern "C" void kernel_launch(void* const* d_in, const int* in_sizes, int n_in,
                              void* d_out, int out_size, void* d_ws, size_t ws_size,
                              hipStream_t stream)
{
  (void)in_sizes; (void)n_in; (void)out_size; (void)ws_size;
  const float* x1  = (const float*)d_in[0];
  const float* x2  = (const float*)d_in[1];
  const float* gg  = (const float*)d_in[2];
  const float* gbe = (const float*)d_in[3];
  const float* gme = (const float*)d_in[4];
  const float* gva = (const float*)d_in[5];
  const float* gw  = (const float*)d_in[6];
  const float* gbi = (const float*)d_in[7];
  const float* tg  = (const float*)d_in[8];
  const float* tbe = (const float*)d_in[9];
  const float* tme = (const float*)d_in[10];
  const float* tva = (const float*)d_in[11];
  const float* tw  = (const float*)d_in[12];
  const float* tbi = (const float*)d_in[13];
  const float* pg  = (const float*)d_in[14];
  const float* pbe = (const float*)d_in[15];
  const float* pme = (const float*)d_in[16];
  const float* pva = (const float*)d_in[17];
  const float* pw  = (const float*)d_in[18];
  const float* pbi = (const float*)d_in[19];
  const float* Ww  = (const float*)d_in[20];
  const float* Wb  = (const float*)d_in[21];
  const float* Wg  = (const float*)d_in[22];
  const float* Wbe = (const float*)d_in[23];
  const float* Wme = (const float*)d_in[24];
  const float* Wva = (const float*)d_in[25];
  // d_in[26..33] (qt/ks/qs/kt) are dead: softmax over singleton axis == 1.

  float* out = (float*)d_out;
  unsigned char* W8 = (unsigned char*)d_ws;

  size_t off = 0;
  auto al = [&](size_t n) { size_t r = off; off += (n + 255) & ~(size_t)255; return r; };
  const size_t oWG  = al(65536);
  const size_t oWTh = al(65536), oWTl = al(65536);
  const size_t oWPh = al(65536), oWPl = al(65536);
  const size_t oWW  = al(65536);
  const size_t oBG = al(512), oBT = al(512), oBP = al(512), oBW = al(1024);
  const size_t oTH = al((size_t)B * 46080), oPH = al((size_t)B * 46080);   // fp32 [90][128]
  const size_t oA1 = al((size_t)B * 32768), oA2 = al((size_t)B * 32768);
  const size_t oS1 = al((size_t)B * 18432), oS2 = al((size_t)B * 18432);
  const size_t oM1 = al((size_t)B * 1024), oXC = al((size_t)B * 384), oXA = al((size_t)B * 4);
  // total ~201.1 MB (<= round-1's proven 203.05 MB)

  k0_fold<<<dim3(640), dim3(256), 0, stream>>>(
      gg, gbe, gme, gva, gw, gbi,
      tg, tbe, tme, tva, tw, tbi,
      pg, pbe, pme, pva, pw, pbi,
      Ww, Wb, Wg, Wbe, Wme, Wva,
      (u16*)(W8 + oWG), (float*)(W8 + oBG),
      (u16*)(W8 + oWTh), (u16*)(W8 + oWTl), (float*)(W8 + oBT),
      (u16*)(W8 + oWPh), (u16*)(W8 + oWPl), (float*)(W8 + oBP),
      (u16*)(W8 + oWW), (float*)(W8 + oBW));

  k1_conv<<<dim3(B), dim3(512), 0, stream>>>(
      x1, x2,
      (const u16*)(W8 + oWG), (const float*)(W8 + oBG),
      (const u16*)(W8 + oWTh), (const u16*)(W8 + oWTl), (const float*)(W8 + oBT),
      (const u16*)(W8 + oWPh), (const u16*)(W8 + oWPl), (const float*)(W8 + oBP),
      (float*)(W8 + oTH), (float*)(W8 + oPH),
      (u16*)out,
      (float*)(W8 + oM1), (float*)(W8 + oXC), (float*)(W8 + oXA));

  k2_attn<<<dim3(B), dim3(256), 0, stream>>>(
      (const float*)(W8 + oTH), (const float*)(W8 + oPH),
      (u16*)(W8 + oA1), (u16*)(W8 + oA2),
      (u16*)(W8 + oS1), (u16*)(W8 + oS2));

  k3_out<<<dim3(B), dim3(256), 0, stream>>>(
      x1, x2,
      (const u16*)(W8 + oA1), (const u16*)(W8 + oA2),
      (const u16*)(W8 + oS1), (const u16*)(W8 + oS2),
      (const u16*)(W8 + oWW), (const float*)(W8 + oBW),
      (const float*)(W8 + oM1), (const float*)(W8 + oXC), (const float*)(W8 + oXA),
      out);
}

// Round 5
// 450.472 us; speedup vs baseline: 4.1063x; 1.0299x over previous
//
#include <hip/hip_runtime.h>

namespace {

constexpr int B = 1024;

using u16 = unsigned short;
using u32 = unsigned int;

typedef __attribute__((ext_vector_type(8))) short bf16x8;
typedef __attribute__((ext_vector_type(4))) float f32x4;

#define MFMA16(a, b, c) __builtin_amdgcn_mfma_f32_16x16x32_bf16(a, b, c, 0, 0, 0)

__device__ __forceinline__ u16 f2bf(float f) {
  u32 u = __builtin_bit_cast(u32, f);
  u += 0x7FFFu + ((u >> 16) & 1u);          // RNE
  return (u16)(u >> 16);
}
__device__ __forceinline__ float bf2f(u16 s) {
  u32 u = ((u32)s) << 16;
  return __builtin_bit_cast(float, u);
}
__device__ __forceinline__ u32 packbf2(float a, float b) {
  return (u32)f2bf(a) | ((u32)f2bf(b) << 16);
}

// ---------------- K0: fold BN into conv weights ----------------
__global__ __launch_bounds__(256) void k0_fold(
    const float* __restrict__ gg, const float* __restrict__ gbe, const float* __restrict__ gme, const float* __restrict__ gva,
    const float* __restrict__ gw, const float* __restrict__ gbi,
    const float* __restrict__ tg, const float* __restrict__ tbe, const float* __restrict__ tme, const float* __restrict__ tva,
    const float* __restrict__ tw, const float* __restrict__ tbi,
    const float* __restrict__ pg, const float* __restrict__ pbe, const float* __restrict__ pme, const float* __restrict__ pva,
    const float* __restrict__ pw, const float* __restrict__ pbi,
    const float* __restrict__ Ww, const float* __restrict__ Wb,
    const float* __restrict__ Wg2, const float* __restrict__ Wbe, const float* __restrict__ Wme, const float* __restrict__ Wva,
    u16* __restrict__ wgo, float* __restrict__ bgo,
    u16* __restrict__ wthi, u16* __restrict__ wtlo, float* __restrict__ bto,
    u16* __restrict__ wphi, u16* __restrict__ wplo, float* __restrict__ bpo,
    u16* __restrict__ wWo, float* __restrict__ bWo)
{
  __shared__ float red[4];
  const int blk = blockIdx.x, tid = threadIdx.x;
  if (blk < 384) {
    const int p = blk >> 7, o = blk & 127;
    const float *ga, *be, *me, *va, *wm, *bi;
    if (p == 0)      { ga = gg; be = gbe; me = gme; va = gva; wm = gw; bi = gbi; }
    else if (p == 1) { ga = tg; be = tbe; me = tme; va = tva; wm = tw; bi = tbi; }
    else             { ga = pg; be = pbe; me = pme; va = pva; wm = pw; bi = pbi; }
    float s = ga[tid] * rsqrtf(va[tid] + 1e-5f);
    float t = be[tid] - me[tid] * s;
    float wv = wm[o * 256 + tid];
    float val = wv * s;
    if (p == 0) {
      wgo[o * 256 + tid] = f2bf(val);
    } else {
      u16 hi = f2bf(val);
      u16 lo = f2bf(val - bf2f(hi));
      if (p == 1) { wthi[o * 256 + tid] = hi; wtlo[o * 256 + tid] = lo; }
      else        { wphi[o * 256 + tid] = hi; wplo[o * 256 + tid] = lo; }
    }
    float part = t * wv;
#pragma unroll
    for (int off = 32; off; off >>= 1) part += __shfl_down(part, off);
    if ((tid & 63) == 0) red[tid >> 6] = part;
    __syncthreads();
    if (tid == 0) {
      float bsum = bi[o] + red[0] + red[1] + red[2] + red[3];
      if (p == 0) bgo[o] = bsum; else if (p == 1) bto[o] = bsum; else bpo[o] = bsum;
    }
  } else {
    const int c = blk - 384;
    float sW = Wg2[c] * rsqrtf(Wva[c] + 1e-5f);
    if (tid < 128) wWo[c * 128 + tid] = f2bf(Ww[c * 128 + tid] * sW);
    if (tid == 0) bWo[c] = Wb[c] * sW + Wbe[c] - Wme[c] * sW;
  }
}

// ---------------- K1: coalesced staged split-convs; dual-orientation packed theta/phi ----------------
// d_out slice layout (u16 units, stride 46080): [0,12288) g ; [12288,36864) thT_pk (u32[96][128]) ; [36864,46080) As (by k2)
__global__ __launch_bounds__(512, 4) void k1_conv(
    const float* __restrict__ x1, const float* __restrict__ x2,
    const u16* __restrict__ wG, const float* __restrict__ bG,
    const u16* __restrict__ wTh, const u16* __restrict__ wTl, const float* __restrict__ bT,
    const u16* __restrict__ wPh, const u16* __restrict__ wPl, const float* __restrict__ bP,
    u32* __restrict__ thRm, u32* __restrict__ phRm,
    u16* __restrict__ outU,
    float* __restrict__ m1t, float* __restrict__ x2cm, float* __restrict__ x1am)
{
  __shared__ u32 qb[64 * 92];       // 23552 B quarter: [ch][v] packed hi|lo
  __shared__ u16 xh[96 * 136];      // 26112 B
  __shared__ u16 xl[96 * 136];      // 26112 B  (total ~75.8 KB -> 2 blocks/CU)
  __shared__ float red[4];
  const int b = blockIdx.x, tid = threadIdx.x;
  const int l = tid & 63, wv = tid >> 6, lr = l & 15, lq = l >> 4;
  const f32x4 zero = {0.f, 0.f, 0.f, 0.f};

  auto doPhase = [&](const float* __restrict__ xb,
                     const u16* __restrict__ Wh, const u16* __restrict__ Wl, const float* __restrict__ biasT,
                     u32* __restrict__ rmDst, u32* __restrict__ pkDst, u16* __restrict__ gDst, bool isX1) {
    f32x4 aT[6], aG[6];
#pragma unroll
    for (int i = 0; i < 6; ++i) { aT[i] = zero; aG[i] = zero; }
    float cs = 0.f;
    for (int h = 0; h < 2; ++h) {
      for (int q = 0; q < 2; ++q) {
        __syncthreads();
        // pass 1: coalesced load + hi/lo split into qb [64ch][92v]
        const float* src = xb + (2 * h + q) * 5760;
        for (int t = tid; t < 2880; t += 512) {
          float2 f = *(const float2*)(src + 2 * t);
          int cl = (2 * t) / 90, v = 2 * t - 90 * cl;
          u16 h0 = f2bf(f.x); u16 l0 = f2bf(f.x - bf2f(h0));
          u16 h1 = f2bf(f.y); u16 l1 = f2bf(f.y - bf2f(h1));
          uint2 w; w.x = (u32)h0 | ((u32)l0 << 16); w.y = (u32)h1 | ((u32)l1 << 16);
          *(uint2*)&qb[cl * 92 + v] = w;
        }
        __syncthreads();
        // pass 2: transpose into xh/xl columns [64q, 64q+64)
        for (int t = tid; t < 1440; t += 512) {
          int v = t % 90, c4 = t / 90;
          u32 p0 = qb[(4 * c4 + 0) * 92 + v], p1 = qb[(4 * c4 + 1) * 92 + v];
          u32 p2 = qb[(4 * c4 + 2) * 92 + v], p3 = qb[(4 * c4 + 3) * 92 + v];
          uint2 hi, lo;
          hi.x = (p0 & 0xFFFFu) | (p1 << 16);
          hi.y = (p2 & 0xFFFFu) | (p3 << 16);
          lo.x = (p0 >> 16) | (p1 & 0xFFFF0000u);
          lo.y = (p2 >> 16) | (p3 & 0xFFFF0000u);
          int base = v * 136 + 64 * q + 4 * c4;
          *(uint2*)&xh[base] = hi;
          *(uint2*)&xl[base] = lo;
        }
        if (q == 1) {   // zero pad rows 90..95 (cols 0..127)
          for (int t = tid; t < 384; t += 512) {
            int v = 90 + (t >> 6), c2 = (t & 63) * 2;
            *(u32*)&xh[v * 136 + c2] = 0u;
            *(u32*)&xl[v * 136 + c2] = 0u;
          }
        }
      }
      __syncthreads();   // half fully staged
      // means (from hi+lo, error ~2^-17 rel)
      if (isX1) {
        if (tid < 128) {
          float s = 0.f;
          for (int v = 0; v < 90; ++v) s += bf2f(xh[v * 136 + tid]) + bf2f(xl[v * 136 + tid]);
          m1t[b * 256 + 128 * h + tid] = s * (1.f / 90.f);
#pragma unroll
          for (int o = 32; o; o >>= 1) s += __shfl_down(s, o);
          if ((tid & 63) == 0) red[(tid >> 6) + 2 * h] = s;
        }
      } else {
        if (tid < 90) {
          float s = 0.f;
          for (int cl = 0; cl < 128; ++cl) s += bf2f(xh[tid * 136 + cl]) + bf2f(xl[tid * 136 + cl]);
          cs += s;
        }
      }
      // MFMA over this half's 128 channels
      for (int kk = 0; kk < 4; ++kk) {
        const int wo = (16 * wv + lr) * 256 + 128 * h + kk * 32 + 8 * lq;
        bf16x8 ah = *(const bf16x8*)(Wh + wo);
        bf16x8 al = *(const bf16x8*)(Wl + wo);
        bf16x8 ag = *(const bf16x8*)(wG + wo);
#pragma unroll
        for (int nt = 0; nt < 6; ++nt) {
          const int bo = (16 * nt + lr) * 136 + kk * 32 + 8 * lq;
          bf16x8 bh = *(const bf16x8*)&xh[bo];
          bf16x8 bl = *(const bf16x8*)&xl[bo];
          aT[nt] = MFMA16(ah, bh, aT[nt]);
          aT[nt] = MFMA16(ah, bl, aT[nt]);
          aT[nt] = MFMA16(al, bh, aT[nt]);
          aG[nt] = MFMA16(ag, bh, aG[nt]);
        }
      }
    }
    __syncthreads();   // red visibility; all LDS reads complete
    // epilogue
    const int c0 = 16 * wv + 4 * lq;
    const float4 bt4 = *(const float4*)(biasT + c0);
    const float4 bg4 = *(const float4*)(bG + c0);
#pragma unroll
    for (int nt = 0; nt < 6; ++nt) {
      const int v = 16 * nt + lr;
      u32 pk0, pk1, pk2, pk3; uint2 gpk;
      if (v < 90) {
        float t0 = aT[nt][0] + bt4.x, t1 = aT[nt][1] + bt4.y;
        float t2 = aT[nt][2] + bt4.z, t3 = aT[nt][3] + bt4.w;
        u16 h0 = f2bf(t0), h1 = f2bf(t1), h2 = f2bf(t2), h3 = f2bf(t3);
        pk0 = (u32)h0 | ((u32)f2bf(t0 - bf2f(h0)) << 16);
        pk1 = (u32)h1 | ((u32)f2bf(t1 - bf2f(h1)) << 16);
        pk2 = (u32)h2 | ((u32)f2bf(t2 - bf2f(h2)) << 16);
        pk3 = (u32)h3 | ((u32)f2bf(t3 - bf2f(h3)) << 16);
        gpk.x = packbf2(aG[nt][0] + bg4.x, aG[nt][1] + bg4.y);
        gpk.y = packbf2(aG[nt][2] + bg4.z, aG[nt][3] + bg4.w);
      } else { pk0 = pk1 = pk2 = pk3 = 0u; gpk.x = 0u; gpk.y = 0u; }
      uint4 q4; q4.x = pk0; q4.y = pk1; q4.z = pk2; q4.w = pk3;
      *(uint4*)(pkDst + v * 128 + c0) = q4;            // thT_pk [v][ci]
      rmDst[(c0 + 0) * 96 + v] = pk0;                  // th_rm [ci][v]
      rmDst[(c0 + 1) * 96 + v] = pk1;
      rmDst[(c0 + 2) * 96 + v] = pk2;
      rmDst[(c0 + 3) * 96 + v] = pk3;
      *(uint2*)(gDst + v * 128 + c0) = gpk;            // g bf16 [v][ci]
    }
    if (isX1) {
      if (tid == 0) x1am[b] = (red[0] + red[1] + red[2] + red[3]) * (1.f / 23040.f);
    } else {
      if (tid < 90) x2cm[b * 96 + tid] = cs * (1.f / 256.f);
    }
  };

  u16* o1 = outU + (size_t)b * 46080;
  u16* o2 = outU + (size_t)(1024 + b) * 46080;
  doPhase(x1 + (size_t)b * 23040, wTh, wTl, bT,
          thRm + (size_t)b * 12288, (u32*)(o1 + 12288), o1, true);
  doPhase(x2 + (size_t)b * 23040, wPh, wPl, bP,
          phRm + (size_t)b * 12288, (u32*)(o2 + 12288), o2, false);
}

// ---------------- K2: fp32-exact scores (pre-split operands) + softmax -> bf16 attn ----------------
__global__ __launch_bounds__(512) void k2_attn(
    const u32* __restrict__ thRm, const u32* __restrict__ phRm,
    u16* __restrict__ outU,
    u16* __restrict__ At1g, u16* __restrict__ At2g)
{
  __shared__ __align__(16) char smem[108544];
  u16* s0 = (u16*)smem;
  float* st = (float*)(smem + 106496);
  float* eL = (float*)smem;

  const int b = blockIdx.x, tid = threadIdx.x;
  const int l = tid & 63, wv = tid >> 6, lr = l & 15, lq = l >> 4;
  const f32x4 zero = {0.f, 0.f, 0.f, 0.f};

  const u32* thRmB = thRm + (size_t)b * 12288;
  const u32* phRmB = phRm + (size_t)b * 12288;
  const u32* thPk = (const u32*)(outU + (size_t)b * 46080 + 12288);
  const u32* phPk = (const u32*)(outU + (size_t)(1024 + b) * 46080 + 12288);
  u32* S1 = (u32*)(outU + (size_t)(1024 + b) * 46080 + 36864);
  u32* S2 = (u32*)(outU + (size_t)b * 46080 + 36864);

  // ===== phase 1: e_time (row-major [ci][v], K=96) =====
  u16* th_hi = s0;
  u16* th_lo = s0 + 13312;
  u16* ph_hi = s0 + 26624;
  u16* ph_lo = s0 + 39936;
  for (int d = tid; d < 6144; d += 512) {
    int ten = (d >= 3072);
    int i = d - 3072 * ten;
    int ci = i / 24, q4 = i - 24 * ci;
    uint4 P = *(const uint4*)((ten ? phRmB : thRmB) + ci * 96 + 4 * q4);
    uint2 hi, lo;
    hi.x = (P.x & 0xFFFFu) | (P.y << 16);
    hi.y = (P.z & 0xFFFFu) | (P.w << 16);
    lo.x = (P.x >> 16) | (P.y & 0xFFFF0000u);
    lo.y = (P.z >> 16) | (P.w & 0xFFFF0000u);
    *(uint2*)((ten ? ph_hi : th_hi) + ci * 104 + 4 * q4) = hi;
    *(uint2*)((ten ? ph_lo : th_lo) + ci * 104 + 4 * q4) = lo;
  }
  __syncthreads();
  f32x4 acc[8];
#pragma unroll
  for (int nt = 0; nt < 8; ++nt) acc[nt] = zero;
#pragma unroll
  for (int kk = 0; kk < 3; ++kk) {
    const int ao = (16 * wv + lr) * 104 + kk * 32 + 8 * lq;
    bf16x8 ah = *(const bf16x8*)&th_hi[ao];
    bf16x8 al = *(const bf16x8*)&th_lo[ao];
#pragma unroll
    for (int nt = 0; nt < 8; ++nt) {
      const int bo = (16 * nt + lr) * 104 + kk * 32 + 8 * lq;
      bf16x8 bh = *(const bf16x8*)&ph_hi[bo];
      bf16x8 bl = *(const bf16x8*)&ph_lo[bo];
      acc[nt] = MFMA16(ah, bh, acc[nt]);
      acc[nt] = MFMA16(ah, bl, acc[nt]);
      acc[nt] = MFMA16(al, bh, acc[nt]);
    }
  }
  __syncthreads();   // staging reads done -> overlay eL
#pragma unroll
  for (int nt = 0; nt < 8; ++nt)
#pragma unroll
    for (int r = 0; r < 4; ++r)
      eL[(16 * nt + lr) * 133 + 16 * wv + 4 * lq + r] = acc[nt][r];
  __syncthreads();
  if (tid < 128) {
    int j = tid; float m = -1e30f;
    for (int i = 0; i < 128; ++i) m = fmaxf(m, eL[j * 133 + i]);
    float s = 0.f;
    for (int i = 0; i < 128; ++i) s += __expf(eL[j * 133 + i] - m);
    st[j] = m; st[128 + j] = 1.f / s;
  } else if (tid < 256) {
    int i = tid - 128; float m = -1e30f;
    for (int j = 0; j < 128; ++j) m = fmaxf(m, eL[j * 133 + i]);
    float s = 0.f;
    for (int j = 0; j < 128; ++j) s += __expf(eL[j * 133 + i] - m);
    st[256 + i] = m; st[384 + i] = 1.f / s;
  }
  __syncthreads();
  {
    u32* A1 = (u32*)(At1g + (size_t)b * 16384);
    u32* A2 = (u32*)(At2g + (size_t)b * 16384);
    for (int d = tid; d < 8192; d += 512) {
      int i = d >> 6, jp = d & 63;
      float m1 = st[256 + i], s1v = st[384 + i];
      float a0 = __expf(eL[(2 * jp) * 133 + i] - m1) * s1v;
      float a1 = __expf(eL[(2 * jp + 1) * 133 + i] - m1) * s1v;
      A1[d] = packbf2(a0, a1);
      float m2 = st[i], s2v = st[128 + i];
      float b0 = __expf(eL[i * 133 + 2 * jp] - m2) * s2v;
      float b1 = __expf(eL[i * 133 + 2 * jp + 1] - m2) * s2v;
      A2[d] = packbf2(b0, b1);
    }
  }
  __syncthreads();

  // ===== phase 2: e_space (transposed [v][ci], K=128) =====
  u16* tTh = s0;
  u16* tTl = s0 + 13056;
  u16* pTh = s0 + 26112;
  u16* pTl = s0 + 39168;
  for (int d = tid; d < 6144; d += 512) {
    int ten = (d >= 3072);
    int i = d - 3072 * ten;
    int v = i >> 5, q4 = i & 31;
    uint4 P = *(const uint4*)((ten ? phPk : thPk) + v * 128 + 4 * q4);
    uint2 hi, lo;
    hi.x = (P.x & 0xFFFFu) | (P.y << 16);
    hi.y = (P.z & 0xFFFFu) | (P.w << 16);
    lo.x = (P.x >> 16) | (P.y & 0xFFFF0000u);
    lo.y = (P.z >> 16) | (P.w & 0xFFFF0000u);
    *(uint2*)((ten ? pTh : tTh) + v * 136 + 4 * q4) = hi;
    *(uint2*)((ten ? pTl : tTl) + v * 136 + 4 * q4) = lo;
  }
  __syncthreads();
  f32x4 accS[5];
#pragma unroll
  for (int it = 0; it < 5; ++it) accS[it] = zero;
#pragma unroll
  for (int it = 0; it < 5; ++it) {
    const int t5 = wv + 8 * it;
    if (t5 < 36) {
      const int mt = t5 / 6, nt = t5 - 6 * (t5 / 6);
#pragma unroll
      for (int kk = 0; kk < 4; ++kk) {
        const int ao = (16 * mt + lr) * 136 + kk * 32 + 8 * lq;
        const int bo = (16 * nt + lr) * 136 + kk * 32 + 8 * lq;
        bf16x8 ah = *(const bf16x8*)&tTh[ao];
        bf16x8 al = *(const bf16x8*)&tTl[ao];
        bf16x8 bh = *(const bf16x8*)&pTh[bo];
        bf16x8 bl = *(const bf16x8*)&pTl[bo];
        accS[it] = MFMA16(ah, bh, accS[it]);
        accS[it] = MFMA16(ah, bl, accS[it]);
        accS[it] = MFMA16(al, bh, accS[it]);
      }
    }
  }
  __syncthreads();
  {
    float* esL = (float*)smem;
#pragma unroll
    for (int it = 0; it < 5; ++it) {
      const int t5 = wv + 8 * it;
      if (t5 < 36) {
        const int mt = t5 / 6, nt = t5 - 6 * (t5 / 6);
#pragma unroll
        for (int r = 0; r < 4; ++r)
          esL[(16 * nt + lr) * 101 + 16 * mt + 4 * lq + r] = accS[it][r];
      }
    }
  }
  __syncthreads();
  {
    float* esL = (float*)smem;
    if (tid < 96) {
      int v = tid; float m = -1e30f;
      for (int w2 = 0; w2 < 90; ++w2) m = fmaxf(m, esL[v * 101 + w2]);
      float s = 0.f;
      for (int w2 = 0; w2 < 90; ++w2) s += __expf(esL[v * 101 + w2] - m);
      st[v] = m; st[128 + v] = 1.f / s;
    } else if (tid >= 128 && tid < 224) {
      int v = tid - 128; float m = -1e30f;
      for (int w2 = 0; w2 < 90; ++w2) m = fmaxf(m, esL[w2 * 101 + v]);
      float s = 0.f;
      for (int w2 = 0; w2 < 90; ++w2) s += __expf(esL[w2 * 101 + v] - m);
      st[256 + v] = m; st[384 + v] = 1.f / s;
    }
  }
  __syncthreads();
  {
    float* esL = (float*)smem;
    for (int d = tid; d < 4608; d += 512) {
      int w2 = d / 48, vp = d - 48 * (d / 48);
      int v0 = 2 * vp, v1 = v0 + 1;
      float a0 = __expf(esL[v0 * 101 + w2] - st[v0]) * st[128 + v0];
      float a1 = __expf(esL[v1 * 101 + w2] - st[v1]) * st[128 + v1];
      S1[d] = packbf2(a0, a1);
      float b0 = __expf(esL[w2 * 101 + v0] - st[256 + v0]) * st[384 + v0];
      float b1 = __expf(esL[w2 * 101 + v1] - st[256 + v1]) * st[384 + v1];
      S2[d] = packbf2(b0, b1);
    }
  }
}

// ---------------- K3: T = At@g, Z = T@As, O = W@Z, residual epilogue ----------------
__global__ __launch_bounds__(256) void k3_out(
    const float* __restrict__ x1, const float* __restrict__ x2,
    const u16* __restrict__ At1g, const u16* __restrict__ At2g,
    const u16* __restrict__ wW, const float* __restrict__ bW,
    const float* __restrict__ m1t, const float* __restrict__ x2cm, const float* __restrict__ x1am,
    float* __restrict__ out)
{
  __shared__ u16 gT[96 * 136];
  __shared__ u16 Tb[128 * 104];
  __shared__ u16 ZT[96 * 136];
  const int b = blockIdx.x, tid = threadIdx.x;
  const int l = tid & 63, wv = tid >> 6, lr = l & 15, lq = l >> 4;
  const f32x4 zero = {0.f, 0.f, 0.f, 0.f};

  float* out1 = out + (size_t)b * 23040;
  float* out2 = out + (size_t)23040 * 1024 + (size_t)b * 23040;
  const u16* g1s = (const u16*)out1;
  const u16* g2s = (const u16*)out2;
  const u16* As1 = (const u16*)out2 + 36864;
  const u16* As2 = (const u16*)out1 + 36864;

  auto phase = [&](const u16* __restrict__ gsrc, const u16* __restrict__ At,
                   const u16* __restrict__ AsT, const float* __restrict__ xres,
                   float* __restrict__ dst, bool modeA) {
    for (int i = tid; i < 1536; i += 256) {
      int v = i >> 4, hh = i & 15;
      *(uint4*)&gT[v * 136 + 8 * hh] = ((const uint4*)gsrc)[i];
    }
    __syncthreads();
#pragma unroll
    for (int ni = 0; ni < 2; ++ni) {
      const int nt = 2 * wv + ni;
      f32x4 acc[6];
#pragma unroll
      for (int i = 0; i < 6; ++i) acc[i] = zero;
#pragma unroll
      for (int kk = 0; kk < 4; ++kk) {
        bf16x8 bb = *(const bf16x8*)(At + (16 * nt + lr) * 128 + kk * 32 + 8 * lq);
#pragma unroll
        for (int mt = 0; mt < 6; ++mt) {
          bf16x8 a = *(const bf16x8*)&gT[(16 * mt + lr) * 136 + kk * 32 + 8 * lq];
          acc[mt] = MFMA16(a, bb, acc[mt]);
        }
      }
#pragma unroll
      for (int mt = 0; mt < 6; ++mt) {
        uint2 pk;
        pk.x = packbf2(acc[mt][0], acc[mt][1]);
        pk.y = packbf2(acc[mt][2], acc[mt][3]);
        *(uint2*)&Tb[(16 * nt + lr) * 104 + 16 * mt + 4 * lq] = pk;
      }
    }
    __syncthreads();
    {
      f32x4 acc[2][6];
#pragma unroll
      for (int i = 0; i < 2; ++i)
#pragma unroll
        for (int j = 0; j < 6; ++j) acc[i][j] = zero;
#pragma unroll
      for (int kk = 0; kk < 3; ++kk) {
        bf16x8 a0 = *(const bf16x8*)&Tb[(16 * (2 * wv) + lr) * 104 + kk * 32 + 8 * lq];
        bf16x8 a1 = *(const bf16x8*)&Tb[(16 * (2 * wv + 1) + lr) * 104 + kk * 32 + 8 * lq];
#pragma unroll
        for (int nt = 0; nt < 6; ++nt) {
          bf16x8 bb = *(const bf16x8*)(AsT + (16 * nt + lr) * 96 + kk * 32 + 8 * lq);
          acc[0][nt] = MFMA16(a0, bb, acc[0][nt]);
          acc[1][nt] = MFMA16(a1, bb, acc[1][nt]);
        }
      }
#pragma unroll
      for (int mi = 0; mi < 2; ++mi) {
        const int mt = 2 * wv + mi;
#pragma unroll
        for (int nt = 0; nt < 6; ++nt) {
          uint2 pk;
          pk.x = packbf2(acc[mi][nt][0], acc[mi][nt][1]);
          pk.y = packbf2(acc[mi][nt][2], acc[mi][nt][3]);
          *(uint2*)&ZT[(16 * nt + lr) * 136 + 16 * mt + 4 * lq] = pk;
        }
      }
    }
    __syncthreads();
    const float am = modeA ? 0.f : x1am[b];
#pragma unroll
    for (int mi = 0; mi < 4; ++mi) {
      const int mt = 4 * wv + mi;
      f32x4 acc[6];
#pragma unroll
      for (int i = 0; i < 6; ++i) acc[i] = zero;
#pragma unroll
      for (int kk = 0; kk < 4; ++kk) {
        bf16x8 a = *(const bf16x8*)(wW + (16 * mt + lr) * 128 + kk * 32 + 8 * lq);
#pragma unroll
        for (int nt = 0; nt < 6; ++nt) {
          bf16x8 bb = *(const bf16x8*)&ZT[(16 * nt + lr) * 136 + kk * 32 + 8 * lq];
          acc[nt] = MFMA16(a, bb, acc[nt]);
        }
      }
      const int c0 = 16 * mt + 4 * lq;
      const float4 bw4 = *(const float4*)(bW + c0);
      float bwA[4] = {bw4.x, bw4.y, bw4.z, bw4.w};
      float mA[4] = {0.f, 0.f, 0.f, 0.f};
      if (modeA) {
        const float4 m4 = *(const float4*)(m1t + b * 256 + c0);
        mA[0] = m4.x; mA[1] = m4.y; mA[2] = m4.z; mA[3] = m4.w;
      }
#pragma unroll
      for (int nt = 0; nt < 6; ++nt) {
        const int v = 16 * nt + lr;
        if (v < 90) {
          const float addv = modeA ? 0.f : (am + x2cm[b * 96 + v]);
#pragma unroll
          for (int r = 0; r < 4; ++r) {
            const int c = c0 + r;
            const float extra = modeA ? mA[r] : addv;
            dst[c * 90 + v] = xres[c * 90 + v] + acc[nt][r] + bwA[r] + extra;
          }
        }
      }
    }
    __syncthreads();
  };

  phase(g2s, At1g + (size_t)b * 16384, As1, x2 + (size_t)b * 23040, out2, true);
  phase(g1s, At2g + (size_t)b * 16384, As2, x1 + (size_t)b * 23040, out1, false);
}

} // namespace

extern "C" void kernel_launch(void* const* d_in, const int* in_sizes, int n_in,
                              void* d_out, int out_size, void* d_ws, size_t ws_size,
                              hipStream_t stream)
{
  (void)in_sizes; (void)n_in; (void)out_size; (void)ws_size;
  const float* x1  = (const float*)d_in[0];
  const float* x2  = (const float*)d_in[1];
  const float* gg  = (const float*)d_in[2];
  const float* gbe = (const float*)d_in[3];
  const float* gme = (const float*)d_in[4];
  const float* gva = (const float*)d_in[5];
  const float* gw  = (const float*)d_in[6];
  const float* gbi = (const float*)d_in[7];
  const float* tg  = (const float*)d_in[8];
  const float* tbe = (const float*)d_in[9];
  const float* tme = (const float*)d_in[10];
  const float* tva = (const float*)d_in[11];
  const float* tw  = (const float*)d_in[12];
  const float* tbi = (const float*)d_in[13];
  const float* pg  = (const float*)d_in[14];
  const float* pbe = (const float*)d_in[15];
  const float* pme = (const float*)d_in[16];
  const float* pva = (const float*)d_in[17];
  const float* pw  = (const float*)d_in[18];
  const float* pbi = (const float*)d_in[19];
  const float* Ww  = (const float*)d_in[20];
  const float* Wb  = (const float*)d_in[21];
  const float* Wg  = (const float*)d_in[22];
  const float* Wbe = (const float*)d_in[23];
  const float* Wme = (const float*)d_in[24];
  const float* Wva = (const float*)d_in[25];
  // d_in[26..33] (qt/ks/qs/kt) are dead: softmax over singleton axis == 1.

  float* out = (float*)d_out;
  unsigned char* W8 = (unsigned char*)d_ws;

  size_t off = 0;
  auto al = [&](size_t n) { size_t r = off; off += (n + 255) & ~(size_t)255; return r; };
  const size_t oWG  = al(65536);
  const size_t oWTh = al(65536), oWTl = al(65536);
  const size_t oWPh = al(65536), oWPl = al(65536);
  const size_t oWW  = al(65536);
  const size_t oBG = al(512), oBT = al(512), oBP = al(512), oBW = al(1024);
  const size_t oRM1 = al((size_t)B * 49152), oRM2 = al((size_t)B * 49152);  // th_rm/ph_rm u32[128][96]
  const size_t oA1 = al((size_t)B * 32768), oA2 = al((size_t)B * 32768);
  const size_t oM1 = al((size_t)B * 1024), oXC = al((size_t)B * 384), oXA = al((size_t)B * 4);
  // total ~168.4 MB (< proven 203 MB); thT_pk/phT_pk/As1/As2 live in unused d_out space.

  k0_fold<<<dim3(640), dim3(256), 0, stream>>>(
      gg, gbe, gme, gva, gw, gbi,
      tg, tbe, tme, tva, tw, tbi,
      pg, pbe, pme, pva, pw, pbi,
      Ww, Wb, Wg, Wbe, Wme, Wva,
      (u16*)(W8 + oWG), (float*)(W8 + oBG),
      (u16*)(W8 + oWTh), (u16*)(W8 + oWTl), (float*)(W8 + oBT),
      (u16*)(W8 + oWPh), (u16*)(W8 + oWPl), (float*)(W8 + oBP),
      (u16*)(W8 + oWW), (float*)(W8 + oBW));

  k1_conv<<<dim3(B), dim3(512), 0, stream>>>(
      x1, x2,
      (const u16*)(W8 + oWG), (const float*)(W8 + oBG),
      (const u16*)(W8 + oWTh), (const u16*)(W8 + oWTl), (const float*)(W8 + oBT),
      (const u16*)(W8 + oWPh), (const u16*)(W8 + oWPl), (const float*)(W8 + oBP),
      (u32*)(W8 + oRM1), (u32*)(W8 + oRM2),
      (u16*)out,
      (float*)(W8 + oM1), (float*)(W8 + oXC), (float*)(W8 + oXA));

  k2_attn<<<dim3(B), dim3(512), 0, stream>>>(
      (const u32*)(W8 + oRM1), (const u32*)(W8 + oRM2),
      (u16*)out,
      (u16*)(W8 + oA1), (u16*)(W8 + oA2));

  k3_out<<<dim3(B), dim3(256), 0, stream>>>(
      x1, x2,
      (const u16*)(W8 + oA1), (const u16*)(W8 + oA2),
      (const u16*)(W8 + oWW), (const float*)(W8 + oBW),
      (const float*)(W8 + oM1), (const float*)(W8 + oXC), (const float*)(W8 + oXA),
      out);
}